// Round 1
// 120.965 us; speedup vs baseline: 1.0549x; 1.0549x over previous
//
#include <hip/hip_runtime.h>
#include <cstdint>

#define HW 200704      // 448*448
#define IMG_W 448
#define NCLS 20
#define NDIM 256
#define NB2 784        // cam tiles per batch (256 px each)
#define LK 260         // padded LDS stride: float4-aligned

// async global->LDS DMA, 4B per lane, dest = wave-uniform base + lane*4
#define ASYNC_COPY4(gp, lp)                                                    \
  __builtin_amdgcn_global_load_lds(                                            \
      (const __attribute__((address_space(1))) void*)(gp),                     \
      (__attribute__((address_space(3))) void*)(lp), 4, 0, 0)

// ---------------------------------------------------------------------------
// K1: fused [pseudo | transpose]. Pseudo is BARRIER-FREE: each wave ballots
// its own present-mask, DMAs its own 64-px column segment of each present
// class row, drains with a per-wave s_waitcnt, consumes its own columns.
// (UNCHANGED this round — control for attribution.)
__global__ __launch_bounds__(256) void k_front(const float* __restrict__ fmap,
                                               float* __restrict__ fmapT,
                                               const float* __restrict__ cam,
                                               const float* __restrict__ cls_label,
                                               const float* __restrict__ hig_p,
                                               const float* __restrict__ low_p,
                                               const float* __restrict__ bg_p,
                                               float* __restrict__ W) {
  __shared__ float sT[NCLS][256];      // 20 KB; row k = k-th present class
  int tid = threadIdx.x;

  if (blockIdx.x >= 2 * NB2) {
    // ---------------- transpose part: fmap [B,256,784] -> fmapT [B,784,256]
    float (*tile)[33] = (float (*)[33]) & sT[0][0];
    int blk = blockIdx.x - 2 * NB2;
    int b = blk / 200;
    int t = blk % 200;
    int dT = t / 25, sT2 = t % 25;
    int ty = tid >> 5, tx = tid & 31;
#pragma unroll
    for (int r = 0; r < 4; ++r) {
      int d = dT * 32 + ty + r * 8;
      int s = sT2 * 32 + tx;
      if (s < 784) tile[ty + r * 8][tx] = fmap[((size_t)(b * 256 + d)) * 784 + s];
    }
    __syncthreads();
#pragma unroll
    for (int r = 0; r < 4; ++r) {
      int s = sT2 * 32 + ty + r * 8;
      int d = dT * 32 + tx;
      if (s < 784) fmapT[((size_t)(b * 784 + s)) * 256 + d] = tile[tx][ty + r * 8];
    }
    return;
  }

  // ---------------- pseudo part (no __syncthreads anywhere)
  int b = blockIdx.x / NB2;
  int blkInB = blockIdx.x % NB2;
  int pix0 = blkInB * 256;
  int wave = tid >> 6, lane = tid & 63;

  // per-wave present mask (bits 0..19), no LDS, no barrier
  bool pres = (lane < NCLS) && (cls_label[b * NCLS + lane] != 0.0f);
  unsigned long long pm = __ballot(pres);
  unsigned mask = (unsigned)(pm & 0xFFFFFu);
  int np = __popc(mask);
  const float* camb = cam + (size_t)b * NCLS * HW + pix0 + wave * 64 + lane;

  // ---- stage: np fire-and-forget 256B DMAs into own column segment ----
  {
    unsigned m = mask;
    for (int k = 0; k < np; ++k) {
      int c = __builtin_ctz(m); m &= m - 1u;
      ASYNC_COPY4(camb + (size_t)c * HW, &sT[k][wave * 64]);
    }
  }
  __builtin_amdgcn_s_waitcnt(0);       // per-wave drain: vmcnt(0) lgkmcnt(0)

  // ---- consume: branchless top-2 over own pixel (ascending class order) ----
  float top1 = -1.0f, sec = -1.0f;
  int cls1 = 0;
  {
    unsigned m = mask;
    for (int k = 0; k < np; ++k) {
      int c = __builtin_ctz(m); m &= m - 1u;
      float x = sT[k][tid];            // own wave's columns only
      bool gt = x > top1;
      sec = gt ? top1 : fmaxf(sec, fminf(x, top1));
      cls1 = gt ? c : cls1;
      top1 = gt ? x : top1;
    }
  }
  if (np < NCLS) sec = fmaxf(sec, 0.0f);   // absent classes contribute exact 0s
  float hig = hig_p[0], low = low_p[0], bg = bg_p[0];
  int pix = pix0 + tid;
  int ps = cls1 + 1;
  if (top1 < hig) ps = 255;
  if (top1 < low) ps = 0;
  if (top1 < bg)  ps = 0;
  if ((top1 - sec < 0.3f) && (top1 > hig)) ps = 255;
  if (ps >= 1 && ps <= NCLS) {
    int cls = ps - 1;
    int y = pix / IMG_W, x = pix % IMG_W;
    float sy = (y + 0.5f) * 0.0625f - 0.5f; sy = fminf(fmaxf(sy, 0.0f), 27.0f);
    float sx = (x + 0.5f) * 0.0625f - 0.5f; sx = fminf(fmaxf(sx, 0.0f), 27.0f);
    int fy0 = (int)sy, fx0 = (int)sx;
    int fy1 = min(fy0 + 1, 27), fx1 = min(fx0 + 1, 27);
    float wy = sy - (float)fy0, wx = sx - (float)fx0;
    float* Wb = W + (size_t)(b * NCLS + cls) * 784;
    atomicAdd(&Wb[fy0 * 28 + fx0], (1.0f - wy) * (1.0f - wx));
    atomicAdd(&Wb[fy0 * 28 + fx1], (1.0f - wy) * wx);
    atomicAdd(&Wb[fy1 * 28 + fx0], wy * (1.0f - wx));
    atomicAdd(&Wb[fy1 * 28 + fx1], wy * wx);
  }
}

// ---------------------------------------------------------------------------
// K2: features, split-K across blocks. (UNCHANGED this round.)
__global__ __launch_bounds__(512) void k_feat(const float* __restrict__ fmapT,
                                              const float* __restrict__ cam,
                                              const float* __restrict__ Wg,
                                              const float* __restrict__ cls_label,
                                              float* __restrict__ P,
                                              float* __restrict__ S,
                                              float* __restrict__ cntW) {
  __shared__ float sW[784];
  __shared__ float sH[2][256];
  __shared__ float sRed[8];
  __shared__ float sCntf;
  __shared__ float wv[8]; __shared__ int wi[8];
  __shared__ float selV; __shared__ int selI;
  __shared__ int sTop[25];
  int bc = blockIdx.x >> 2, part = blockIdx.x & 3;
  int b = bc / NCLS;
  int tid = threadIdx.x;
  int dim = tid & 255, h = tid >> 8;
  if (cls_label[bc] == 0.0f) return;     // combine writes 0 for absent rows

  for (int s = tid; s < 784; s += 512) sW[s] = Wg[(size_t)bc * 784 + s];
  __syncthreads();
  // cnt = sum(W row); non-negative terms -> ==0 test exact
  {
    float cs = sW[tid >= 512 ? 0 : tid];               // guarded below
    cs = (tid < 512) ? sW[tid] : 0.0f;
    if (tid < 272) cs += sW[tid + 512];
    for (int off = 32; off > 0; off >>= 1) cs += __shfl_xor(cs, off, 64);
    if ((tid & 63) == 0) sRed[tid >> 6] = cs;
    __syncthreads();
    if (tid == 0) {
      float s = 0.0f;
      for (int w = 0; w < 8; ++w) s += sRed[w];
      sCntf = s;
    }
    __syncthreads();
  }
  float cntf = sCntf;
  const float* fT = fmapT + (size_t)b * 784 * 256;

  if (cntf > 0.0f) {
    int s0 = part * 196;
    if (h == 0) {
      float a0 = 0.0f, a1 = 0.0f;
      for (int s = s0; s < s0 + 196; s += 4) {
        a0 += sW[s]     * fT[(size_t)(s)     * 256 + dim];
        a1 += sW[s + 1] * fT[(size_t)(s + 1) * 256 + dim];
      }
      sH[0][dim] = a0 + a1;
    } else {
      float a2 = 0.0f, a3 = 0.0f;
      for (int s = s0; s < s0 + 196; s += 4) {
        a2 += sW[s + 2] * fT[(size_t)(s + 2) * 256 + dim];
        a3 += sW[s + 3] * fT[(size_t)(s + 3) * 256 + dim];
      }
      sH[1][dim] = a2 + a3;
    }
    __syncthreads();
    if (tid < 256)
      P[(size_t)(bc * 4 + part) * 256 + tid] = sH[0][tid] + sH[1][tid];
    if (part == 0 && tid == 0) cntW[bc] = cntf;
  } else if (part == 0) {
    // exact top-25 (JAX tie-break) by full scan; statistically never taken
    if (tid == 0) cntW[bc] = 0.0f;
    const float* camc = cam + (size_t)bc * HW;
    float lastV = 3.0e38f; int lastI = -1;
    for (int r = 0; r < 25; ++r) {
      float bv = -1.0e30f; int bi = 0x7fffffff;
      for (int p = tid; p < HW; p += 512) {
        float vv2 = camc[p];
        if (((vv2 < lastV) || (vv2 == lastV && p > lastI)) &&
            ((vv2 > bv) || (vv2 == bv && p < bi))) { bv = vv2; bi = p; }
      }
      for (int off = 32; off > 0; off >>= 1) {
        float ov = __shfl_xor(bv, off, 64);
        int   oi = __shfl_xor(bi, off, 64);
        if (ov > bv || (ov == bv && oi < bi)) { bv = ov; bi = oi; }
      }
      if ((tid & 63) == 0) { wv[tid >> 6] = bv; wi[tid >> 6] = bi; }
      __syncthreads();
      if (tid == 0) {
        for (int w = 1; w < 8; ++w)
          if (wv[w] > bv || (wv[w] == bv && wi[w] < bi)) { bv = wv[w]; bi = wi[w]; }
        selV = bv; selI = bi; sTop[r] = bi;
      }
      __syncthreads();
      lastV = selV; lastI = selI;
    }
    if (tid < 256) {
      float at = 0.0f;
      for (int r = 0; r < 25; ++r) {
        int p = sTop[r];
        int y = p / IMG_W, x = p % IMG_W;
        float sy = (y + 0.5f) * 0.0625f - 0.5f; sy = fminf(fmaxf(sy, 0.0f), 27.0f);
        float sx = (x + 0.5f) * 0.0625f - 0.5f; sx = fminf(fmaxf(sx, 0.0f), 27.0f);
        int fy0 = (int)sy, fx0 = (int)sx;
        int fy1 = min(fy0 + 1, 27), fx1 = min(fx0 + 1, 27);
        float wy = sy - (float)fy0, wx = sx - (float)fx0;
        at += (1.0f - wy) * (1.0f - wx) * fT[(size_t)(fy0 * 28 + fx0) * 256 + tid]
            + (1.0f - wy) * wx          * fT[(size_t)(fy0 * 28 + fx1) * 256 + tid]
            + wy          * (1.0f - wx) * fT[(size_t)(fy1 * 28 + fx0) * 256 + tid]
            + wy          * wx          * fT[(size_t)(fy1 * 28 + fx1) * 256 + tid];
      }
      S[(size_t)bc * 256 + tid] = at * (1.0f / 25.0f);
    }
  }
}

// ---------------------------------------------------------------------------
// K3 (NEW): parallel loss precompute — one block per (batch, class) row.
// Replaces the single-CU heavy phases of the old k_loss. All dot/norm/reduce
// bodies are VERBATIM copies of the old (passing) code so the arithmetic
// trees are bit-identical. The only sequential dependency in the reference
// (b=1 cos depends on which fc columns were EMA-updated by b=0 qualify) is
// resolved by computing BOTH b=1 cos variants here and selecting in k_final.
__global__ __launch_bounds__(256) void k_pre(const float* __restrict__ P,
                                             const float* __restrict__ S,
                                             const float* __restrict__ cntW,
                                             const float* __restrict__ cls_label,
                                             const float* __restrict__ proj_w,
                                             const float* __restrict__ fc_init,
                                             float* __restrict__ BCEg,
                                             float* __restrict__ COS0,
                                             float* __restrict__ COS1V) {
  __shared__ float sOwn[LK];                 // this block's fsm row
  __shared__ float sFc[NCLS * LK], sPw[NCLS * LK];
  __shared__ float sF0[NCLS * LK], sFv[NCLS * LK];   // b==1 only
  __shared__ float sLog[NCLS];
  __shared__ float sNC[NCLS], sNCv[NCLS];
  __shared__ int   sZC[NCLS], sZCv[NCLS];
  __shared__ float sNI[1]; __shared__ int sZI[1];
  int tid = threadIdx.x;
  int b = blockIdx.x / NCLS, i = blockIdx.x % NCLS;

  for (int idx = tid; idx < NCLS * NDIM; idx += 256) {
    int r = idx >> 8, d = idx & 255;
    sFc[r * LK + d] = fc_init[idx];
    sPw[r * LK + d] = proj_w[idx];
  }
  { // own fsm row: verbatim combine tree ((P0+P1)+(P2+P3))/max(c,1)
    int bc = b * NCLS + i, d = tid;
    float v = 0.0f;
    if (cls_label[bc] != 0.0f) {
      float c = cntW[bc];
      if (c > 0.0f) {
        const float* p = P + (size_t)bc * 1024 + d;
        v = ((p[0] + p[256]) + (p[512] + p[768])) / fmaxf(c, 1.0f);
      } else {
        v = S[(size_t)bc * 256 + d];
      }
    }
    sOwn[d] = v;
  }
  if (b == 1) { // b==1 blocks also need all batch-0 fsm rows for fc variants
    for (int idx = tid; idx < NCLS * NDIM; idx += 256) {
      int bc = idx >> 8, d = idx & 255;
      float v = 0.0f;
      if (cls_label[bc] != 0.0f) {
        float c = cntW[bc];
        if (c > 0.0f) {
          const float* p = P + (size_t)bc * 1024 + d;
          v = ((p[0] + p[256]) + (p[512] + p[768])) / fmaxf(c, 1.0f);
        } else {
          v = S[(size_t)bc * 256 + d];
        }
      }
      sF0[bc * LK + d] = v;
    }
  }
  __syncthreads();
  if (b == 1) { // EMA-variant fc rows: verbatim update expression
    for (int idx = tid; idx < NCLS * NDIM; idx += 256) {
      int r = idx >> 8, d = idx & 255;
      sFv[r * LK + d] = 0.95f * sFc[r * LK + d] + 0.05f * sF0[r * LK + d];
    }
    __syncthreads();
  }

  // ---- norms: fc_init rows (g<20) + own fsm row (g==20), verbatim tree ----
  {
    int g = tid >> 3, sub = tid & 7;
    if (g <= 20) {
      const float* row = (g < 20) ? &sFc[g * LK] : sOwn;
      float a0 = 0.0f, a1 = 0.0f, a2 = 0.0f, a3 = 0.0f;
      int d0 = sub * 32;
#pragma unroll
      for (int d = d0; d < d0 + 32; d += 8) {
        float4 x = *(const float4*)&row[d];
        float4 y = *(const float4*)&row[d + 4];
        a0 += x.x * x.x + x.y * x.y;
        a1 += x.z * x.z + x.w * x.w;
        a2 += y.x * y.x + y.y * y.y;
        a3 += y.z * y.z + y.w * y.w;
      }
      float s = (a0 + a1) + (a2 + a3);
      s += __shfl_xor(s, 1, 64);
      s += __shfl_xor(s, 2, 64);
      s += __shfl_xor(s, 4, 64);
      if (sub == 0) {
        if (g < 20) { sNC[g] = fmaxf(sqrtf(s), 1e-12f); sZC[g] = (s == 0.0f); }
        else        { sNI[0] = fmaxf(sqrtf(s), 1e-12f); sZI[0] = (s == 0.0f); }
      }
    }
  }
  __syncthreads();
  if (b == 1) { // variant-fc norms (same verbatim body)
    int g = tid >> 3, sub = tid & 7;
    if (g < 20) {
      const float* row = &sFv[g * LK];
      float a0 = 0.0f, a1 = 0.0f, a2 = 0.0f, a3 = 0.0f;
      int d0 = sub * 32;
#pragma unroll
      for (int d = d0; d < d0 + 32; d += 8) {
        float4 x = *(const float4*)&row[d];
        float4 y = *(const float4*)&row[d + 4];
        a0 += x.x * x.x + x.y * x.y;
        a1 += x.z * x.z + x.w * x.w;
        a2 += y.x * y.x + y.y * y.y;
        a3 += y.z * y.z + y.w * y.w;
      }
      float s = (a0 + a1) + (a2 + a3);
      s += __shfl_xor(s, 1, 64);
      s += __shfl_xor(s, 2, 64);
      s += __shfl_xor(s, 4, 64);
      if (sub == 0) { sNCv[g] = fmaxf(sqrtf(s), 1e-12f); sZCv[g] = (s == 0.0f); }
    }
    __syncthreads();
  }

  // ---- logits row: verbatim P1 dot body ----
  if (tid < NCLS) {
    const float* ra = sOwn;
    const float* rb = &sPw[tid * LK];
    float a0 = 0, a1 = 0, a2 = 0, a3 = 0, a4 = 0, a5 = 0, a6 = 0, a7 = 0;
    for (int d = 0; d < 256; d += 16) {
      float4 x0 = *(const float4*)&ra[d],      y0 = *(const float4*)&rb[d];
      float4 x1 = *(const float4*)&ra[d + 4],  y1 = *(const float4*)&rb[d + 4];
      float4 x2 = *(const float4*)&ra[d + 8],  y2 = *(const float4*)&rb[d + 8];
      float4 x3 = *(const float4*)&ra[d + 12], y3 = *(const float4*)&rb[d + 12];
      a0 += x0.x * y0.x + x0.y * y0.y;  a1 += x0.z * y0.z + x0.w * y0.w;
      a2 += x1.x * y1.x + x1.y * y1.y;  a3 += x1.z * y1.z + x1.w * y1.w;
      a4 += x2.x * y2.x + x2.y * y2.y;  a5 += x2.z * y2.z + x2.w * y2.w;
      a6 += x3.x * y3.x + x3.y * y3.y;  a7 += x3.z * y3.z + x3.w * y3.w;
    }
    sLog[tid] = ((a0 + a1) + (a2 + a3)) + ((a4 + a5) + (a6 + a7));
  }
  __syncthreads();

  // ---- final parallel phase: BCE (wave0) | cos vs fc_init (wave1) |
  //      cos vs EMA-variant fc (wave2, b==1 only) — all independent ----
  if (tid < 32) { // verbatim P3 body for row (b,i)
    int jj = tid;
    float l = (jj < NCLS) ? sLog[jj] : -3.0e38f;
    float m = l;
#pragma unroll
    for (int off = 1; off < 32; off <<= 1) m = fmaxf(m, __shfl_xor(m, off, 64));
    float e = (jj < NCLS) ? expf(l - m) : 0.0f;
    float sS = e;
#pragma unroll
    for (int off = 1; off < 32; off <<= 1) sS += __shfl_xor(sS, off, 64);
    float term = 0.0f;
    if (jj < NCLS) {
      float p = e / sS;
      term = (jj == i) ? fmaxf(logf(p), -100.0f) : fmaxf(log1pf(-p), -100.0f);
    }
#pragma unroll
    for (int off = 1; off < 32; off <<= 1) term += __shfl_xor(term, off, 64);
    if (jj == 0) BCEg[b * NCLS + i] = -term / 20.0f;
  }
  if (tid >= 64 && tid < 64 + 2 * NCLS) { // cos vs fc_init (verbatim pair dot)
    int j = (tid - 64) >> 1, sub = tid & 1;
    float c0;
    if (sZI[0] || sZC[j]) c0 = 0.0f;
    else {
      const float* ra = sOwn;
      const float* rb = &sFc[j * LK];
      float a0 = 0.0f, a1 = 0.0f, a2 = 0.0f, a3 = 0.0f;
      int d0 = sub * 128;
      for (int d = d0; d < d0 + 128; d += 8) {
        float4 x  = *(const float4*)&ra[d];
        float4 y  = *(const float4*)&rb[d];
        float4 x2 = *(const float4*)&ra[d + 4];
        float4 y2 = *(const float4*)&rb[d + 4];
        a0 += x.x * y.x + x.y * y.y;
        a1 += x.z * y.z + x.w * y.w;
        a2 += x2.x * y2.x + x2.y * y2.y;
        a3 += x2.z * y2.z + x2.w * y2.w;
      }
      float acc = (a0 + a1) + (a2 + a3);
      acc += __shfl_xor(acc, 1, 64);
      c0 = fabsf(acc / (sNI[0] * sNC[j]));
    }
    if (sub == 0) {
      float cv = fminf(fmaxf(c0, 1e-5f), 1.0f - 1e-5f);
      if (b == 0) COS0[i * NCLS + j] = cv;
      else        COS1V[i * NCLS + j] = cv;            // variant 0 (fc unchanged)
    }
  }
  if (b == 1 && tid >= 128 && tid < 128 + 2 * NCLS) {  // cos vs EMA-variant fc
    int j = (tid - 128) >> 1, sub = tid & 1;
    float c0;
    if (sZI[0] || sZCv[j]) c0 = 0.0f;
    else {
      const float* ra = sOwn;
      const float* rb = &sFv[j * LK];
      float a0 = 0.0f, a1 = 0.0f, a2 = 0.0f, a3 = 0.0f;
      int d0 = sub * 128;
      for (int d = d0; d < d0 + 128; d += 8) {
        float4 x  = *(const float4*)&ra[d];
        float4 y  = *(const float4*)&rb[d];
        float4 x2 = *(const float4*)&ra[d + 4];
        float4 y2 = *(const float4*)&rb[d + 4];
        a0 += x.x * y.x + x.y * y.y;
        a1 += x.z * y.z + x.w * y.w;
        a2 += x2.x * y2.x + x2.y * y2.y;
        a3 += x2.z * y2.z + x2.w * y2.w;
      }
      float acc = (a0 + a1) + (a2 + a3);
      acc += __shfl_xor(acc, 1, 64);
      c0 = fabsf(acc / (sNI[0] * sNCv[j]));
    }
    if (sub == 0)
      COS1V[400 + i * NCLS + j] = fminf(fmaxf(c0, 1e-5f), 1.0f - 1e-5f);  // variant 1
  }
}

// ---------------------------------------------------------------------------
// K4 (NEW): tiny sequential tail — row reductions, qualify, per-column
// variant select for b=1, serial loss accumulation (all verbatim from old
// k_loss's per-batch epilogue).
__global__ __launch_bounds__(1024) void k_final(const float* __restrict__ BCEg,
                                                const float* __restrict__ COS0,
                                                const float* __restrict__ COS1V,
                                                const float* __restrict__ cls_label,
                                                float* __restrict__ out) {
  __shared__ float sCos[400];
  __shared__ float sBCE[2][NCLS], sRow[NCLS];
  __shared__ int   sQual[NCLS];
  __shared__ float sPres[2][NCLS];
  __shared__ float sScal[2];
  int tid = threadIdx.x;

  if (tid < 400) sCos[tid] = COS0[tid];
  if (tid < 40) { sBCE[tid / NCLS][tid % NCLS] = BCEg[tid];
                  sPres[tid / NCLS][tid % NCLS] = cls_label[tid]; }
  if (tid == 0) { sScal[0] = 0.0f; sScal[1] = 0.0f; }
  __syncthreads();

  for (int b = 0; b < 2; ++b) {
    if (b == 1) {
      // fc column j was EMA-updated iff qualify0[j] -> select cos variant
      if (tid < 400) {
        int j = tid % NCLS;
        sCos[tid] = sQual[j] ? COS1V[400 + tid] : COS1V[tid];
      }
      __syncthreads();
    }
    { // verbatim contrib/qualify phase
      int i = tid >> 5, jj = tid & 31;
      if (i < NCLS) {
        float pres = (sPres[b][i] > 0.5f) ? 1.0f : 0.0f;
        float contrib = 0.0f, omv = -3.0e38f;
        if (jj < NCLS) {
          float c0 = sCos[i * NCLS + jj];
          float ident = (jj == i) ? pres : 0.0f;
          contrib = ident * logf(c0) + (1.0f - ident) * log1pf(-c0);
          if (jj != i) omv = c0;
        }
#pragma unroll
        for (int off = 1; off < 32; off <<= 1) {
          contrib += __shfl_xor(contrib, off, 64);
          omv = fmaxf(omv, __shfl_xor(omv, off, 64));
        }
        if (jj == 0) { sRow[i] = contrib; sQual[i] = (pres > 0.5f && omv < 0.6f) ? 1 : 0; }
      }
    }
    __syncthreads();
    if (tid == 0) { // verbatim serial accumulation
      float s = 0.0f;
      for (int r = 0; r < NCLS; ++r) s += sRow[r];
      sScal[0] -= s / 400.0f;
      float add = 0.0f; int nq = 0;
      for (int r = 0; r < NCLS; ++r) if (sQual[r]) { add += sBCE[b][r]; nq++; }
      float lc = sScal[1] + add;
      if (nq > 0) lc = lc / fmaxf((float)nq, 1.0f);
      sScal[1] = lc;
    }
    __syncthreads();
  }
  if (tid == 0) out[0] = sScal[0] + sScal[1];
}

// ---------------------------------------------------------------------------
extern "C" void kernel_launch(void* const* d_in, const int* in_sizes, int n_in,
                              void* d_out, int out_size, void* d_ws, size_t ws_size,
                              hipStream_t stream) {
  const float* fmap      = (const float*)d_in[0];
  const float* cam       = (const float*)d_in[1];
  const float* cls_label = (const float*)d_in[2];
  const float* proj_w    = (const float*)d_in[3];
  const float* fc_init   = (const float*)d_in[4];
  const float* hig       = (const float*)d_in[5];
  const float* low       = (const float*)d_in[6];
  const float* bg        = (const float*)d_in[7];
  float* out = (float*)d_out;

  char* ws = (char*)d_ws;
  float* W     = (float*)(ws);                 // 125440 B
  float* cntW  = (float*)(ws + 125440);        // 160 B
  float* P     = (float*)(ws + 125600);        // 40*4*256*4 = 163840 B
  float* S     = (float*)(ws + 289440);        // 40*256*4   = 40960 B
  float* fmapT = (float*)(ws + 330400);        // 1605632 B -> end 1936032
  float* BCEg  = (float*)(ws + 1936032);       // 2*20*4   = 160 B
  float* COS0v = (float*)(ws + 1936192);       // 400*4    = 1600 B
  float* COS1V = (float*)(ws + 1937792);       // 2*400*4  = 3200 B

  hipMemsetAsync(ws, 0, 125440, stream);       // zero W only
  k_front<<<2 * NB2 + 400,  256, 0, stream>>>(fmap, fmapT, cam, cls_label,
                                              hig, low, bg, W);
  k_feat <<<          160,  512, 0, stream>>>(fmapT, cam, W, cls_label, P, S, cntW);
  k_pre  <<<   2 * NCLS,    256, 0, stream>>>(P, S, cntW, cls_label, proj_w,
                                              fc_init, BCEg, COS0v, COS1V);
  k_final<<<            1, 1024, 0, stream>>>(BCEg, COS0v, COS1V, cls_label, out);
}